// Round 1
// baseline (2315.130 us; speedup 1.0000x reference)
//
#include <hip/hip_runtime.h>
#include <hip/hip_bf16.h>
#include <stdint.h>

#define Bsz 512
#define Tsz 128
#define Fsz 512
#define Hsz 512
#define G3  1536   // 3H
#define KK  1024   // F + H (concat K)

typedef __attribute__((ext_vector_type(8))) short bf16x8;
typedef __attribute__((ext_vector_type(4))) float f32x4;

__device__ __forceinline__ unsigned short f2bf(float x) {
    union { float f; unsigned int u; } v; v.f = x;
    unsigned int r = v.u + 0x7FFFu + ((v.u >> 16) & 1u);   // round-to-nearest-even
    return (unsigned short)(r >> 16);
}

__device__ __forceinline__ float fsigmoid(float x) {
    return 1.0f / (1.0f + __expf(-x));
}
__device__ __forceinline__ float ftanh(float x) {
    // tanh(x) = 2*sigmoid(2x) - 1 ; saturates correctly for large |x|
    return 2.0f / (1.0f + __expf(-2.0f * x)) - 1.0f;
}

// x[b][t][f] fp32  ->  xT[t][b][f] bf16   (block-transpose: rows move whole)
__global__ void convert_x_kernel(const float* __restrict__ x, unsigned short* __restrict__ xT) {
    const long n4 = (long)Bsz * Tsz * Fsz / 4;
    for (long idx = (long)blockIdx.x * blockDim.x + threadIdx.x; idx < n4;
         idx += (long)gridDim.x * blockDim.x) {
        long e = idx * 4;
        int f  = (int)(e & (Fsz - 1));
        long row = e >> 9;               // b*T + t   (F=512=2^9)
        int t = (int)(row & (Tsz - 1));  // T=128=2^7
        int b = (int)(row >> 7);
        float4 v = reinterpret_cast<const float4*>(x)[idx];
        ushort4 o;
        o.x = f2bf(v.x); o.y = f2bf(v.y); o.z = f2bf(v.z); o.w = f2bf(v.w);
        long oa = ((((long)t * Bsz + b) << 9) + f) >> 2;
        reinterpret_cast<ushort4*>(xT)[oa] = o;
    }
}

// wT[n][k] = (k<F ? kernel[k][n] : rkernel[k-F][n])  as bf16,  n in [0,3H), k in [0,1024)
__global__ void prep_w_kernel(const float* __restrict__ kern, const float* __restrict__ rkern,
                              unsigned short* __restrict__ wT) {
    int idx = blockIdx.x * blockDim.x + threadIdx.x;   // exactly G3*KK threads
    int n = idx >> 10;
    int k = idx & 1023;
    float v = (k < Fsz) ? kern[(size_t)k * G3 + n] : rkern[(size_t)(k - Fsz) * G3 + n];
    wT[idx] = f2bf(v);
}

// One GRU time step. Grid (B/32, H/32) = 16x16 blocks, 256 threads (4 waves).
// Each wave: 16 rows x 16 cols, all 3 gates. K = 1024 (x-part 0..511, h-part 512..1023).
// h-gate keeps x-part and h-part in separate accumulators (reset_after=True).
template<int USE_XT>
__global__ __launch_bounds__(256) void gru_step_kernel(
    const unsigned short* __restrict__ xT,     // [T][B][F] bf16 (if USE_XT)
    const float* __restrict__ x,               // [B][T][F] fp32 (fallback)
    const unsigned short* __restrict__ wT,     // [3H][1024] bf16
    const unsigned short* __restrict__ hin_bf, // [B][H] bf16
    const float* __restrict__ hin_f,           // [B][H] fp32
    unsigned short* __restrict__ hout_bf,
    float* __restrict__ hout_f,
    const float* __restrict__ bias_i,
    const float* __restrict__ bias_r,
    int t)
{
    const int lane = threadIdx.x & 63;
    const int w    = threadIdx.x >> 6;
    const int l16  = lane & 15;
    const int kg   = lane >> 4;           // 0..3
    const int rb   = blockIdx.x * 32;     // batch tile base
    const int cb   = blockIdx.y * 32;     // h-col tile base
    const int wr   = (w >> 1) * 16;       // wave row offset
    const int wc   = (w & 1) * 16;        // wave col offset

    const int arow = rb + wr + l16;       // A row (batch) for this lane
    const int ccol = cb + wc + l16;       // h-column for B frags / epilogue

    f32x4 acc_z  = {0.f, 0.f, 0.f, 0.f};
    f32x4 acc_r  = {0.f, 0.f, 0.f, 0.f};
    f32x4 acc_xh = {0.f, 0.f, 0.f, 0.f};
    f32x4 acc_hh = {0.f, 0.f, 0.f, 0.f};

    const unsigned short* bz = wT + (size_t)(0 * Hsz + ccol) * KK;
    const unsigned short* br = wT + (size_t)(1 * Hsz + ccol) * KK;
    const unsigned short* bh = wT + (size_t)(2 * Hsz + ccol) * KK;

    const unsigned short* ax  = xT + ((size_t)t * Bsz + arow) * Fsz;
    const float*          axf = x  + ((size_t)arow * Tsz + t) * Fsz;
    const unsigned short* ah  = hin_bf + (size_t)arow * Hsz;

    #pragma unroll
    for (int kb = 0; kb < 32; ++kb) {
        const int ko = kb * 32 + kg * 8;
        bf16x8 a;
        if (kb < 16) {
            if (USE_XT) {
                a = *reinterpret_cast<const bf16x8*>(ax + ko);
            } else {
                float4 v0 = *reinterpret_cast<const float4*>(axf + ko);
                float4 v1 = *reinterpret_cast<const float4*>(axf + ko + 4);
                a[0] = (short)f2bf(v0.x); a[1] = (short)f2bf(v0.y);
                a[2] = (short)f2bf(v0.z); a[3] = (short)f2bf(v0.w);
                a[4] = (short)f2bf(v1.x); a[5] = (short)f2bf(v1.y);
                a[6] = (short)f2bf(v1.z); a[7] = (short)f2bf(v1.w);
            }
        } else {
            a = *reinterpret_cast<const bf16x8*>(ah + (ko - Fsz));
        }
        bf16x8 fz = *reinterpret_cast<const bf16x8*>(bz + ko);
        bf16x8 fr = *reinterpret_cast<const bf16x8*>(br + ko);
        bf16x8 fh = *reinterpret_cast<const bf16x8*>(bh + ko);
        acc_z = __builtin_amdgcn_mfma_f32_16x16x32_bf16(a, fz, acc_z, 0, 0, 0);
        acc_r = __builtin_amdgcn_mfma_f32_16x16x32_bf16(a, fr, acc_r, 0, 0, 0);
        if (kb < 16)
            acc_xh = __builtin_amdgcn_mfma_f32_16x16x32_bf16(a, fh, acc_xh, 0, 0, 0);
        else
            acc_hh = __builtin_amdgcn_mfma_f32_16x16x32_bf16(a, fh, acc_hh, 0, 0, 0);
    }

    const float bi_z = bias_i[ccol];
    const float bi_r = bias_i[Hsz + ccol];
    const float bi_h = bias_i[2 * Hsz + ccol];
    const float br_z = bias_r[ccol];
    const float br_r = bias_r[Hsz + ccol];
    const float br_h = bias_r[2 * Hsz + ccol];

    #pragma unroll
    for (int j = 0; j < 4; ++j) {
        const int b = rb + wr + kg * 4 + j;     // C/D: row = (lane>>4)*4 + reg
        const size_t o = (size_t)b * Hsz + ccol;
        float z  = fsigmoid(acc_z[j] + bi_z + br_z);
        float r  = fsigmoid(acc_r[j] + bi_r + br_r);
        float hh = ftanh(acc_xh[j] + bi_h + r * (acc_hh[j] + br_h));
        float hp = hin_f[o];
        float hn = z * hp + (1.0f - z) * hh;
        hout_f[o]  = hn;
        hout_bf[o] = f2bf(hn);
    }
}

// out[b] = h[b,:] . dense_w + dense_b   (one wave per batch row)
__global__ void dense_kernel(const float* __restrict__ h, const float* __restrict__ dw,
                             const float* __restrict__ db, float* __restrict__ out) {
    const int wid  = (blockIdx.x * blockDim.x + threadIdx.x) >> 6;
    const int lane = threadIdx.x & 63;
    if (wid >= Bsz) return;
    const float* hr = h + (size_t)wid * Hsz;
    float s = 0.f;
    #pragma unroll
    for (int i = 0; i < 2; ++i) {
        float4 hv = reinterpret_cast<const float4*>(hr)[lane * 2 + i];
        float4 wv = reinterpret_cast<const float4*>(dw)[lane * 2 + i];
        s += hv.x * wv.x + hv.y * wv.y + hv.z * wv.z + hv.w * wv.w;
    }
    #pragma unroll
    for (int off = 32; off > 0; off >>= 1) s += __shfl_down(s, off, 64);
    if (lane == 0) out[wid] = s + db[0];
}

extern "C" void kernel_launch(void* const* d_in, const int* in_sizes, int n_in,
                              void* d_out, int out_size, void* d_ws, size_t ws_size,
                              hipStream_t stream) {
    const float* x      = (const float*)d_in[0];
    const float* kern   = (const float*)d_in[1];
    const float* rkern  = (const float*)d_in[2];
    const float* bias_i = (const float*)d_in[3];
    const float* bias_r = (const float*)d_in[4];
    const float* dw     = (const float*)d_in[5];
    const float* db     = (const float*)d_in[6];
    float* out = (float*)d_out;

    char* ws = (char*)d_ws;
    size_t off = 0;
    unsigned short* wT = (unsigned short*)(ws + off); off += (size_t)G3 * KK * 2;   // 3 MB
    float* h_f0 = (float*)(ws + off); off += (size_t)Bsz * Hsz * 4;                 // 1 MB
    float* h_f1 = (float*)(ws + off); off += (size_t)Bsz * Hsz * 4;                 // 1 MB
    unsigned short* h_b0 = (unsigned short*)(ws + off); off += (size_t)Bsz * Hsz * 2;
    unsigned short* h_b1 = (unsigned short*)(ws + off); off += (size_t)Bsz * Hsz * 2;
    unsigned short* xT = (unsigned short*)(ws + off);
    const size_t xt_bytes = (size_t)Tsz * Bsz * Fsz * 2;                            // 64 MB
    const bool use_xt = (off + xt_bytes) <= ws_size;

    prep_w_kernel<<<(G3 * KK) / 256, 256, 0, stream>>>(kern, rkern, wT);
    hipMemsetAsync(h_f0, 0, (size_t)Bsz * Hsz * 4, stream);
    hipMemsetAsync(h_b0, 0, (size_t)Bsz * Hsz * 2, stream);
    if (use_xt) convert_x_kernel<<<4096, 256, 0, stream>>>(x, xT);

    float* hf[2] = {h_f0, h_f1};
    unsigned short* hb[2] = {h_b0, h_b1};
    dim3 grid(Bsz / 32, Hsz / 32);
    for (int t = 0; t < Tsz; ++t) {
        const int c = t & 1, n = c ^ 1;
        if (use_xt)
            gru_step_kernel<1><<<grid, 256, 0, stream>>>(xT, x, wT, hb[c], hf[c],
                                                         hb[n], hf[n], bias_i, bias_r, t);
        else
            gru_step_kernel<0><<<grid, 256, 0, stream>>>(xT, x, wT, hb[c], hf[c],
                                                         hb[n], hf[n], bias_i, bias_r, t);
    }
    // after t=127 the final state is in buffer 0
    dense_kernel<<<Bsz / 4, 256, 0, stream>>>(hf[0], dw, db, out);
}

// Round 2
// 1105.432 us; speedup vs baseline: 2.0943x; 2.0943x over previous
//
#include <hip/hip_runtime.h>
#include <hip/hip_bf16.h>
#include <stdint.h>

#define Bsz 512
#define Tsz 128
#define Fsz 512
#define Hsz 512
#define G3  1536   // 3H
#define KK  1024   // F + H (concat K)

typedef __attribute__((ext_vector_type(8))) short bf16x8;
typedef __attribute__((ext_vector_type(4))) float f32x4;

__device__ __forceinline__ unsigned short f2bf(float x) {
    union { float f; unsigned int u; } v; v.f = x;
    unsigned int r = v.u + 0x7FFFu + ((v.u >> 16) & 1u);   // round-to-nearest-even
    return (unsigned short)(r >> 16);
}

__device__ __forceinline__ float fsigmoid(float x) {
    return 1.0f / (1.0f + __expf(-x));
}
__device__ __forceinline__ float ftanh(float x) {
    return 2.0f / (1.0f + __expf(-2.0f * x)) - 1.0f;
}

// ---------------------------------------------------------------------------
// Swizzled fragment layouts (so a wave's MFMA-fragment load is lane-contiguous):
//   weights wTs : elem (g, n, k)  -> ((g*32+cT)*32 + kb)*512 + kg*128 + l16*8 + e
//                 cT=n>>4 l16=n&15 kb=k>>5 kg=(k>>3)&3 e=k&7
//   x        xs : elem (t, b, f)  -> ((t*32+rT)*16 + kb)*512 + kg*128 + l16*8 + e
//                 rT=b>>4 l16=b&15 kb=f>>5 kg kg=(f>>3)&3 e=f&7
//   h (bf16) hs : elem (b, n)     -> (rT*16 + kb)*512 + kg*128 + l16*8 + e   (kb=n>>5)
// A wave-load at  base + lane*8  is then one coalesced 1KB transaction.
// ---------------------------------------------------------------------------

__global__ void prep_w_kernel(const float* __restrict__ kern, const float* __restrict__ rkern,
                              unsigned short* __restrict__ wTs) {
    int idx = blockIdx.x * blockDim.x + threadIdx.x;   // exactly 3*512*1024 threads
    int e   = idx & 7;
    int l16 = (idx >> 3) & 15;
    int kg  = (idx >> 7) & 3;
    int kb  = (idx >> 9) & 31;
    int cT  = (idx >> 14) & 31;
    int g   = idx >> 19;                // 0..2
    int n = cT * 16 + l16;
    int k = kb * 32 + kg * 8 + e;
    float v = (k < Fsz) ? kern[(size_t)k * G3 + g * Hsz + n]
                        : rkern[(size_t)(k - Fsz) * G3 + g * Hsz + n];
    wTs[idx] = f2bf(v);
}

// One thread per 8-elem output chunk: source is 8 contiguous floats of x[b][t][f..f+8)
__global__ void convert_x_kernel(const float* __restrict__ x, unsigned short* __restrict__ xs) {
    const int nchunks = Bsz * Tsz * Fsz / 8;   // 4194304
    for (int c = blockIdx.x * blockDim.x + threadIdx.x; c < nchunks;
         c += gridDim.x * blockDim.x) {
        int l16 = c & 15;
        int kg  = (c >> 4) & 3;
        int kb  = (c >> 6) & 15;
        int rT  = (c >> 10) & 31;
        int t   = c >> 15;
        int b   = rT * 16 + l16;
        int f0  = kb * 32 + kg * 8;
        const float* src = x + ((size_t)b * Tsz + t) * Fsz + f0;
        float4 v0 = *reinterpret_cast<const float4*>(src);
        float4 v1 = *reinterpret_cast<const float4*>(src + 4);
        bf16x8 o;
        o[0] = (short)f2bf(v0.x); o[1] = (short)f2bf(v0.y);
        o[2] = (short)f2bf(v0.z); o[3] = (short)f2bf(v0.w);
        o[4] = (short)f2bf(v1.x); o[5] = (short)f2bf(v1.y);
        o[6] = (short)f2bf(v1.z); o[7] = (short)f2bf(v1.w);
        *reinterpret_cast<bf16x8*>(xs + (size_t)c * 8) = o;
    }
}

// One GRU step. Grid (16,16), 1024 threads = 16 waves:
//   wave w: kq=w>>2 (K-quarter), wr=((w>>1)&1)*16, wc=(w&1)*16.
//   kq 0,1 -> x-projection halves (kb 0..15); kq 2,3 -> h-projection halves.
//   LDS reduction combines the 4 K-partials; kq==0 waves run the gate epilogue.
__global__ __launch_bounds__(1024) void gru_step_kernel(
    const unsigned short* __restrict__ xs,      // swizzled x, bf16
    const unsigned short* __restrict__ wTs,     // swizzled weights, bf16
    const unsigned short* __restrict__ hin_bs,  // swizzled h, bf16
    const float* __restrict__ hin_f,            // [B][H] fp32 carry
    unsigned short* __restrict__ hout_bs,
    float* __restrict__ hout_f,
    const float* __restrict__ bias_i,
    const float* __restrict__ bias_r,
    int t)
{
    const int tid  = threadIdx.x;
    const int lane = tid & 63;
    const int w    = tid >> 6;            // 0..15
    const int kq   = w >> 2;              // 0..3
    const int wr   = ((w >> 1) & 1) * 16;
    const int wc   = (w & 1) * 16;
    const int rb   = blockIdx.x * 32;
    const int cb   = blockIdx.y * 32;
    const int rT   = (rb + wr) >> 4;      // 16-row A tile index
    const int cT   = (cb + wc) >> 4;      // 16-col B tile index
    const int l16  = lane & 15;
    const int kg   = lane >> 4;

    f32x4 a0 = {0.f, 0.f, 0.f, 0.f};      // z partial
    f32x4 a1 = {0.f, 0.f, 0.f, 0.f};      // r partial
    f32x4 a2 = {0.f, 0.f, 0.f, 0.f};      // hh partial (x-part for kq<2, h-part for kq>=2)

    const unsigned short* wz = wTs + ((size_t)(0 * 32 + cT) * 32) * 512 + lane * 8;
    const unsigned short* wr_ = wTs + ((size_t)(1 * 32 + cT) * 32) * 512 + lane * 8;
    const unsigned short* wh = wTs + ((size_t)(2 * 32 + cT) * 32) * 512 + lane * 8;

    if (kq < 2) {
        const unsigned short* pa =
            xs + (((size_t)t * 32 + rT) * 16 + kq * 8) * 512 + lane * 8;
        #pragma unroll
        for (int i = 0; i < 8; ++i) {
            const int kb = kq * 8 + i;               // 0..15 (x K-blocks)
            bf16x8 a  = *reinterpret_cast<const bf16x8*>(pa + (size_t)i * 512);
            bf16x8 fz = *reinterpret_cast<const bf16x8*>(wz + (size_t)kb * 512);
            bf16x8 fr = *reinterpret_cast<const bf16x8*>(wr_ + (size_t)kb * 512);
            bf16x8 fh = *reinterpret_cast<const bf16x8*>(wh + (size_t)kb * 512);
            a0 = __builtin_amdgcn_mfma_f32_16x16x32_bf16(a, fz, a0, 0, 0, 0);
            a1 = __builtin_amdgcn_mfma_f32_16x16x32_bf16(a, fr, a1, 0, 0, 0);
            a2 = __builtin_amdgcn_mfma_f32_16x16x32_bf16(a, fh, a2, 0, 0, 0);
        }
    } else {
        const unsigned short* pa =
            hin_bs + ((size_t)rT * 16 + (kq - 2) * 8) * 512 + lane * 8;
        #pragma unroll
        for (int i = 0; i < 8; ++i) {
            const int kbh = (kq - 2) * 8 + i;        // 0..15 (h K-blocks)
            const int kbw = 16 + kbh;                // weight K-block
            bf16x8 a  = *reinterpret_cast<const bf16x8*>(pa + (size_t)i * 512);
            bf16x8 fz = *reinterpret_cast<const bf16x8*>(wz + (size_t)kbw * 512);
            bf16x8 fr = *reinterpret_cast<const bf16x8*>(wr_ + (size_t)kbw * 512);
            bf16x8 fh = *reinterpret_cast<const bf16x8*>(wh + (size_t)kbw * 512);
            a0 = __builtin_amdgcn_mfma_f32_16x16x32_bf16(a, fz, a0, 0, 0, 0);
            a1 = __builtin_amdgcn_mfma_f32_16x16x32_bf16(a, fr, a1, 0, 0, 0);
            a2 = __builtin_amdgcn_mfma_f32_16x16x32_bf16(a, fh, a2, 0, 0, 0);
        }
    }

    // K-partial reduction through LDS. stride-17 padding: banks = kg*4+j*17+l16 -> conflict-free
    __shared__ float red[12][3][272];
    if (kq != 0) {
        const int widx = w - 4;
        #pragma unroll
        for (int j = 0; j < 4; ++j) {
            const int i = (kg * 4 + j) * 17 + l16;
            red[widx][0][i] = a0[j];
            red[widx][1][i] = a1[j];
            red[widx][2][i] = a2[j];
        }
    }
    __syncthreads();

    if (kq == 0) {
        const int n = cb + wc + l16;
        const float bi_z = bias_i[n];
        const float bi_r = bias_i[Hsz + n];
        const float bi_h = bias_i[2 * Hsz + n];
        const float br_z = bias_r[n];
        const float br_r = bias_r[Hsz + n];
        const float br_h = bias_r[2 * Hsz + n];
        const int kb_n = n >> 5, kg_n = (n >> 3) & 3, e_n = n & 7;
        #pragma unroll
        for (int j = 0; j < 4; ++j) {
            const int i = (kg * 4 + j) * 17 + l16;
            const int b = rb + wr + kg * 4 + j;        // C/D row = (lane>>4)*4 + reg
            const size_t o = (size_t)b * Hsz + n;
            float zs  = a0[j] + red[w][0][i] + red[w + 4][0][i] + red[w + 8][0][i];
            float rs  = a1[j] + red[w][1][i] + red[w + 4][1][i] + red[w + 8][1][i];
            float xh  = a2[j] + red[w][2][i];                    // x-part of h gate
            float hhh = red[w + 4][2][i] + red[w + 8][2][i];     // h-part of h gate
            float z  = fsigmoid(zs + bi_z + br_z);
            float r  = fsigmoid(rs + bi_r + br_r);
            float hh = ftanh(xh + bi_h + r * (hhh + br_h));
            float hp = hin_f[o];
            float hn = z * hp + (1.0f - z) * hh;
            hout_f[o] = hn;
            hout_bs[((size_t)rT * 16 + kb_n) * 512 + kg_n * 128 + (kg * 4 + j) * 8 + e_n] =
                f2bf(hn);
        }
    }
}

// out[b] = h[b,:] . dense_w + dense_b   (one wave per batch row)
__global__ void dense_kernel(const float* __restrict__ h, const float* __restrict__ dw,
                             const float* __restrict__ db, float* __restrict__ out) {
    const int wid  = (blockIdx.x * blockDim.x + threadIdx.x) >> 6;
    const int lane = threadIdx.x & 63;
    if (wid >= Bsz) return;
    const float* hr = h + (size_t)wid * Hsz;
    float s = 0.f;
    #pragma unroll
    for (int i = 0; i < 2; ++i) {
        float4 hv = reinterpret_cast<const float4*>(hr)[lane * 2 + i];
        float4 wv = reinterpret_cast<const float4*>(dw)[lane * 2 + i];
        s += hv.x * wv.x + hv.y * wv.y + hv.z * wv.z + hv.w * wv.w;
    }
    #pragma unroll
    for (int off = 32; off > 0; off >>= 1) s += __shfl_down(s, off, 64);
    if (lane == 0) out[wid] = s + db[0];
}

extern "C" void kernel_launch(void* const* d_in, const int* in_sizes, int n_in,
                              void* d_out, int out_size, void* d_ws, size_t ws_size,
                              hipStream_t stream) {
    const float* x      = (const float*)d_in[0];
    const float* kern   = (const float*)d_in[1];
    const float* rkern  = (const float*)d_in[2];
    const float* bias_i = (const float*)d_in[3];
    const float* bias_r = (const float*)d_in[4];
    const float* dw     = (const float*)d_in[5];
    const float* db     = (const float*)d_in[6];
    float* out = (float*)d_out;

    char* ws = (char*)d_ws;
    size_t off = 0;
    unsigned short* wTs = (unsigned short*)(ws + off); off += (size_t)G3 * KK * 2;  // 3 MB
    float* h_f0 = (float*)(ws + off); off += (size_t)Bsz * Hsz * 4;                 // 1 MB
    float* h_f1 = (float*)(ws + off); off += (size_t)Bsz * Hsz * 4;                 // 1 MB
    unsigned short* h_b0 = (unsigned short*)(ws + off); off += (size_t)Bsz * Hsz * 2;
    unsigned short* h_b1 = (unsigned short*)(ws + off); off += (size_t)Bsz * Hsz * 2;
    unsigned short* xs = (unsigned short*)(ws + off);                               // 64 MB

    prep_w_kernel<<<(G3 * KK) / 256, 256, 0, stream>>>(kern, rkern, wTs);
    hipMemsetAsync(h_f0, 0, (size_t)Bsz * Hsz * 4, stream);
    hipMemsetAsync(h_b0, 0, (size_t)Bsz * Hsz * 2, stream);
    convert_x_kernel<<<4096, 256, 0, stream>>>(x, xs);

    float* hf[2] = {h_f0, h_f1};
    unsigned short* hb[2] = {h_b0, h_b1};
    dim3 grid(16, 16);
    for (int t = 0; t < Tsz; ++t) {
        const int c = t & 1, n = c ^ 1;
        gru_step_kernel<<<grid, 1024, 0, stream>>>(xs, wTs, hb[c], hf[c],
                                                   hb[n], hf[n], bias_i, bias_r, t);
    }
    // after t=127 the final state is in buffer 0
    dense_kernel<<<Bsz / 4, 256, 0, stream>>>(hf[0], dw, db, out);
}